// Round 9
// baseline (318.008 us; speedup 1.0000x reference)
//
#include <hip/hip_runtime.h>
#include <math.h>

#define DD 1024
#define HH1 4096
#define HH2 4096

typedef __attribute__((ext_vector_type(8))) short bf16x8;
typedef __attribute__((ext_vector_type(4))) float f32x4;
typedef unsigned short ushort_t;

// ws layout (bytes), total 42,008,576 (proven available R3-R6). NO OVERLAPS:
//   [0)        u0  (4096 f32)                       [0,     16384)
//   [16384)    q   (4096 f32)                       [16384, 32768)
//   [32768)    cv  (4096 f32)                       [32768, 49152)
//   [49152)    cdP (512 f32)  block partials of Σc·d [49152, 51200)
//   [51200)    P   (512 f32)  block partials of GEMM [51200, 53248)
//   [53248)    cnts(2 u32)    barrier + finale ctr   [53248, 53256)
//   [53256, 65536) unused
//   [65536)    A' = bf16(W2 .* s)  4096x4096        [65536,    33619968)
//   [33619968) B' = bf16(W1^T)     1024x4096        [33619968, 42008576)
#define WS_FAST_BYTES 42008576ull

__device__ inline void wave_reduce2(float& a, float& b) {
  #pragma unroll
  for (int off = 32; off > 0; off >>= 1) {
    a += __shfl_down(a, off, 64);
    b += __shfl_down(b, off, 64);
  }
}

// fp32 -> bf16 RNE
__device__ inline unsigned int f2b(float f) {
  union { float f; unsigned int u; } v; v.f = f;
  return (v.u + 0x7FFFu + ((v.u >> 16) & 1u)) >> 16;
}
__device__ inline unsigned int pack2(float a, float b) {
  return f2b(a) | (f2b(b) << 16);
}

// async global->LDS, 16 B/lane; lds dst = wave-uniform base + lane*16
__device__ inline void gl_lds16(const void* g, void* l) {
  __builtin_amdgcn_global_load_lds(
      (const __attribute__((address_space(1))) unsigned int*)g,
      (__attribute__((address_space(3))) unsigned int*)l, 16, 0, 0);
}

// kA: layer-1 + W1 transpose-convert (R5-proven). Block = 8 rows of W1.
// Also zeroes the two ws counters (visible to kBCD via kernel boundary).
__global__ __launch_bounds__(256) void kA_l1t(
    const float* __restrict__ W1, const float* __restrict__ x,
    const float* __restrict__ b1, float* __restrict__ u0,
    float* __restrict__ q, ushort_t* __restrict__ Bp,
    unsigned int* __restrict__ cnts) {
  __shared__ ushort_t T[8][1032];  // stride 1032: conflict-free
  const int tid = threadIdx.x, lane = tid & 63, w = tid >> 6;
  const int h0 = blockIdx.x * 8;
  if (blockIdx.x == 0 && tid < 2) cnts[tid] = 0u;
  const float4* x4 = (const float4*)x;
  #pragma unroll
  for (int rr = 0; rr < 2; ++rr) {
    int row = w * 2 + rr;  // 0..7
    const float4* rp = (const float4*)(W1 + (size_t)(h0 + row) * DD);
    float dot = 0.f, sq = 0.f;
    #pragma unroll
    for (int j = 0; j < 4; ++j) {
      int idx = j * 64 + lane;
      float4 wv = rp[idx];
      float4 xv = x4[idx];
      dot += wv.x * xv.x + wv.y * xv.y + wv.z * xv.z + wv.w * xv.w;
      sq  += wv.x * wv.x + wv.y * wv.y + wv.z * wv.z + wv.w * wv.w;
      uint2 pk;
      pk.x = pack2(wv.x, wv.y);
      pk.y = pack2(wv.z, wv.w);
      *(uint2*)&T[row][idx * 4] = pk;
    }
    wave_reduce2(dot, sq);
    if (lane == 0) {
      float a0 = dot + b1[h0 + row];
      float u = tanhf(a0);
      float s = 1.f - u * u;
      u0[h0 + row] = u;
      q[h0 + row] = -2.f * u * s * sq;
    }
  }
  __syncthreads();
  #pragma unroll
  for (int j = 0; j < 4; ++j) {
    int i = j * 256 + tid;
    union { uint4 v; ushort_t us[8]; } pk;
    #pragma unroll
    for (int h = 0; h < 8; ++h) pk.us[h] = T[h][i];
    *(uint4*)(Bp + (size_t)i * HH1 + h0) = pk.v;  // 16B-aligned (h0*2)
  }
}

struct SmemGemm {
  ushort_t As[128][128];  // 32 KB
  ushort_t Bs[64][128];   // 16 KB
  float red[8];
};

// kBCD: grid 512 x 256. Co-residency: LDS 49.2KB -> 3 blk/CU;
// __launch_bounds__(256,2) -> VGPR<=256 -> >=2 blk/CU; 512 = 2x256 slots.
//  B: block b owns g-rows [8b,8b+8): cv + A'[g,:]=bf16(W2[g,:]*s);
//     block-partial cdP[b] = Σ_rows c·d  (NO 4096-wide cd array anymore)
//  barrier: fence+atomic+spin (bounded), R6-proven visibility idiom
//  C: R5-proven 128(g)x64(i) BK=128 GEMM tile; P[b]=Σ cv[g]*M[g,i]^2
//  D: counter-gated last block: out = Σ cdP - 2*Σ P
__global__ __launch_bounds__(256, 2) void kBCD(
    const float* __restrict__ W2, const float* __restrict__ b2,
    const float* __restrict__ W3, const float* __restrict__ u0,
    const float* __restrict__ q, ushort_t* __restrict__ Ap,
    const ushort_t* __restrict__ Bp, float* __restrict__ cv,
    float* __restrict__ cdP, float* __restrict__ P,
    unsigned int* __restrict__ cnts, float* __restrict__ out) {
  __shared__ SmemGemm sm;
  const int tid = threadIdx.x;
  const int lane = tid & 63;
  const int w = tid >> 6;
  const int b = blockIdx.x;

  // ---------------- Phase B: layer-2 + A' convert ----------------
  {
    const f32x4* u4 = (const f32x4*)u0;
    const f32x4* q4 = (const f32x4*)q;
    float cdsum = 0.f;  // meaningful on tid 0 only
    for (int rr = 0; rr < 8; ++rr) {
      int g = b * 8 + rr;
      const float4* row = (const float4*)(W2 + (size_t)g * HH1);
      float zacc = 0.f, dacc = 0.f;
      #pragma unroll
      for (int it = 0; it < 4; ++it) {
        int j = tid + it * 256;  // 0..1023
        float4 wv = row[j];
        f32x4 u = u4[j];
        f32x4 qv = q4[j];
        float sx = 1.f - u[0] * u[0], sy = 1.f - u[1] * u[1];
        float sz = 1.f - u[2] * u[2], sw = 1.f - u[3] * u[3];
        zacc += wv.x * u[0] + wv.y * u[1] + wv.z * u[2] + wv.w * u[3];
        dacc += wv.x * qv[0] + wv.y * qv[1] + wv.z * qv[2] + wv.w * qv[3];
        uint2 pk;
        pk.x = pack2(wv.x * sx, wv.y * sy);
        pk.y = pack2(wv.z * sz, wv.w * sw);
        *(uint2*)(Ap + (size_t)g * HH1 + j * 4) = pk;
      }
      wave_reduce2(zacc, dacc);
      if (lane == 0) { sm.red[w * 2] = zacc; sm.red[w * 2 + 1] = dacc; }
      __syncthreads();
      if (tid == 0) {
        float z = sm.red[0] + sm.red[2] + sm.red[4] + sm.red[6] + b2[g];
        float d = sm.red[1] + sm.red[3] + sm.red[5] + sm.red[7];
        float v = tanhf(z);
        float t = 1.f - v * v;
        float c = W3[g] * t;
        cv[g] = c * v;
        cdsum += c * d;
      }
      __syncthreads();
    }
    if (tid == 0) cdP[b] = cdsum;
  }

  // -------- software device-scope barrier (B -> C), bounded spin --------
  {
    __syncthreads();  // all threads' stores drained (vmcnt(0) before s_barrier)
    if (tid == 0) {
      __threadfence();              // release: publish Ap/cv/cdP
      atomicAdd(&cnts[0], 1u);
      int guard = 0;
      while (__hip_atomic_load(&cnts[0], __ATOMIC_RELAXED,
                               __HIP_MEMORY_SCOPE_AGENT) < 512u &&
             guard < (1 << 23)) {
        __builtin_amdgcn_s_sleep(8);
        ++guard;
      }
    }
    __syncthreads();
    __threadfence();                // acquire: see other blocks' Ap/cv/cdP
  }

  // ---------------- Phase C: bf16 MFMA GEMM tile (R5-proven) ----------------
  {
    const int wm = w >> 1, wn = w & 1;
    const int xcd = b & 7, j = b >> 3;
    const int g0 = (xcd * 4 + (j & 3)) * 128;
    const int i0 = (j >> 2) * 64;
    const int srow = lane >> 4;   // 0..3
    const int schk = lane & 15;   // phys 16B chunk

    f32x4 acc[4][2];
    const f32x4 zero = {0.f, 0.f, 0.f, 0.f};
    #pragma unroll
    for (int mt = 0; mt < 4; ++mt)
      #pragma unroll
      for (int nt = 0; nt < 2; ++nt) acc[mt][nt] = zero;

    const int fr = lane & 15;
    const int fc = lane >> 4;

    for (int ko = 0; ko < HH1 / 128; ++ko) {
      const int k0 = ko * 128;
      #pragma unroll
      for (int p = 0; p < 8; ++p) {
        int row = w * 32 + p * 4 + srow;
        int lc = schk ^ (row & 15);
        gl_lds16(Ap + (size_t)(g0 + row) * HH1 + k0 + lc * 8,
                 (char*)&sm.As[0][0] + (w * 32 + p * 4) * 256 + lane * 16);
      }
      #pragma unroll
      for (int p = 0; p < 4; ++p) {
        int row = w * 16 + p * 4 + srow;
        int lc = schk ^ (row & 15);
        gl_lds16(Bp + (size_t)(i0 + row) * HH1 + k0 + lc * 8,
                 (char*)&sm.Bs[0][0] + (w * 16 + p * 4) * 256 + lane * 16);
      }
      __syncthreads();  // drains vmcnt (global_load_lds)
      #pragma unroll
      for (int kk = 0; kk < 4; ++kk) {
        bf16x8 af[4], bfv[2];
        #pragma unroll
        for (int mt = 0; mt < 4; ++mt) {
          int row = wm * 64 + mt * 16 + fr;
          af[mt] = *(const bf16x8*)&sm.As[row][((kk * 4 + fc) ^ (row & 15)) * 8];
        }
        #pragma unroll
        for (int nt = 0; nt < 2; ++nt) {
          int row = wn * 32 + nt * 16 + fr;
          bfv[nt] = *(const bf16x8*)&sm.Bs[row][((kk * 4 + fc) ^ (row & 15)) * 8];
        }
        #pragma unroll
        for (int mt = 0; mt < 4; ++mt)
          #pragma unroll
          for (int nt = 0; nt < 2; ++nt)
            acc[mt][nt] = __builtin_amdgcn_mfma_f32_16x16x32_bf16(
                af[mt], bfv[nt], acc[mt][nt], 0, 0, 0);
      }
      __syncthreads();
    }

    float part = 0.f;
    #pragma unroll
    for (int mt = 0; mt < 4; ++mt) {
      #pragma unroll
      for (int r = 0; r < 4; ++r) {
        int g = g0 + wm * 64 + mt * 16 + fc * 4 + r;
        float c = cv[g];
        float ss = 0.f;
        #pragma unroll
        for (int nt = 0; nt < 2; ++nt) {
          float v = acc[mt][nt][r];
          ss += v * v;
        }
        part += c * ss;
      }
    }
    #pragma unroll
    for (int off = 32; off > 0; off >>= 1) part += __shfl_down(part, off, 64);
    if (lane == 0) sm.red[w] = part;
    __syncthreads();

    // -------------- Phase D: counter-gated last-block finale (R6-proven) ----
    if (tid == 0) {
      P[b] = sm.red[0] + sm.red[1] + sm.red[2] + sm.red[3];
      __threadfence();
      unsigned int old = atomicAdd(&cnts[1], 1u);
      sm.red[4] = (old == 511u) ? 1.f : 0.f;
    }
    __syncthreads();
    if (sm.red[4] != 0.f) {
      __threadfence();  // acquire all P/cdP stores
      float a = 0.f, bb = 0.f;
      for (int jj = tid; jj < 512; jj += 256) {
        a += cdP[jj];
        bb += P[jj];
      }
      float v = a - 2.f * bb;
      #pragma unroll
      for (int off = 32; off > 0; off >>= 1) v += __shfl_down(v, off, 64);
      if (lane == 0) sm.red[w] = v;
      __syncthreads();
      if (tid == 0) out[0] = sm.red[0] + sm.red[1] + sm.red[2] + sm.red[3];
    }
  }
}

// ---------------- fallback (fp32, tiny ws; R1-proven) ----------------

__global__ __launch_bounds__(256) void k1_slow(
    const float* __restrict__ W1, const float* __restrict__ x,
    const float* __restrict__ b1, float* __restrict__ u0,
    float* __restrict__ q, float* __restrict__ s_out,
    float* __restrict__ out) {
  int h = blockIdx.x;
  int tid = threadIdx.x;
  const float4* row = (const float4*)(W1 + (size_t)h * DD);
  const float4* x4 = (const float4*)x;
  float4 w = row[tid];
  float4 xv = x4[tid];
  float dot = w.x * xv.x + w.y * xv.y + w.z * xv.z + w.w * xv.w;
  float sq = w.x * w.x + w.y * w.y + w.z * w.z + w.w * w.w;
  wave_reduce2(dot, sq);
  __shared__ float lds[8];
  int lane = tid & 63, wid = tid >> 6;
  if (lane == 0) { lds[wid * 2] = dot; lds[wid * 2 + 1] = sq; }
  __syncthreads();
  if (tid == 0) {
    float dsum = lds[0] + lds[2] + lds[4] + lds[6];
    float rsum = lds[1] + lds[3] + lds[5] + lds[7];
    float a0 = dsum + b1[h];
    float u = tanhf(a0);
    float s = 1.f - u * u;
    u0[h] = u;
    s_out[h] = s;
    q[h] = -2.f * u * s * rsum;
    if (h == 0) out[0] = 0.f;
  }
}

__global__ __launch_bounds__(256) void k2_slow(
    const float* __restrict__ W2, const float* __restrict__ b2,
    const float* __restrict__ W3, const float* __restrict__ u0,
    const float* __restrict__ q, float* __restrict__ cv,
    float* __restrict__ out) {
  int g = blockIdx.x;
  int tid = threadIdx.x;
  const float4* row = (const float4*)(W2 + (size_t)g * HH1);
  const float4* u4 = (const float4*)u0;
  const float4* q4 = (const float4*)q;
  float zacc = 0.f, dacc = 0.f;
  for (int j = tid; j < HH1 / 4; j += 256) {
    float4 w = row[j];
    float4 u = u4[j];
    float4 qq = q4[j];
    zacc += w.x * u.x + w.y * u.y + w.z * u.z + w.w * u.w;
    dacc += w.x * qq.x + w.y * qq.y + w.z * qq.z + w.w * qq.w;
  }
  wave_reduce2(zacc, dacc);
  __shared__ float lds[8];
  int lane = tid & 63, wid = tid >> 6;
  if (lane == 0) { lds[wid * 2] = zacc; lds[wid * 2 + 1] = dacc; }
  __syncthreads();
  if (tid == 0) {
    float z = lds[0] + lds[2] + lds[4] + lds[6] + b2[g];
    float d = lds[1] + lds[3] + lds[5] + lds[7];
    float v = tanhf(z);
    float t = 1.f - v * v;
    float c = W3[g] * t;
    cv[g] = c * v;
    atomicAdd(out, c * d);
  }
}

__global__ __launch_bounds__(256) void k4_slow(
    const float* __restrict__ W2, const float* __restrict__ W1,
    const float* __restrict__ s, const float* __restrict__ cv,
    float* __restrict__ out) {
  __shared__ float As[32][68];
  __shared__ float Bs[32][68];
  int tid = threadIdx.x;
  int g0 = blockIdx.y * 64;
  int i0 = blockIdx.x * 64;
  int tr = (tid / 16) * 4;
  int tc = (tid % 16) * 4;
  float acc[4][4] = {};
  for (int k0 = 0; k0 < HH1; k0 += 32) {
    for (int ll = tid; ll < (64 * 32 / 4); ll += 256) {
      int row = ll / 8;
      int c4 = ll % 8;
      float4 w = *(const float4*)(W2 + (size_t)(g0 + row) * HH1 + k0 + c4 * 4);
      float4 sv = *(const float4*)(s + k0 + c4 * 4);
      As[c4 * 4 + 0][row] = w.x * sv.x;
      As[c4 * 4 + 1][row] = w.y * sv.y;
      As[c4 * 4 + 2][row] = w.z * sv.z;
      As[c4 * 4 + 3][row] = w.w * sv.w;
    }
    for (int ll = tid; ll < (32 * 64 / 4); ll += 256) {
      int row = ll / 16;
      int c4 = ll % 16;
      float4 w = *(const float4*)(W1 + (size_t)(k0 + row) * DD + i0 + c4 * 4);
      *(float4*)&Bs[row][c4 * 4] = w;
    }
    __syncthreads();
    #pragma unroll
    for (int k = 0; k < 32; ++k) {
      float4 av = *(const float4*)&As[k][tr];
      float4 bv = *(const float4*)&Bs[k][tc];
      float a_[4] = {av.x, av.y, av.z, av.w};
      float b_[4] = {bv.x, bv.y, bv.z, bv.w};
      #pragma unroll
      for (int r = 0; r < 4; ++r)
        #pragma unroll
        for (int c = 0; c < 4; ++c)
          acc[r][c] += a_[r] * b_[c];
    }
    __syncthreads();
  }
  float contrib = 0.f;
  #pragma unroll
  for (int r = 0; r < 4; ++r) {
    float ss = acc[r][0] * acc[r][0] + acc[r][1] * acc[r][1] +
               acc[r][2] * acc[r][2] + acc[r][3] * acc[r][3];
    contrib += cv[g0 + tr + r] * ss;
  }
  #pragma unroll
  for (int off = 32; off > 0; off >>= 1) contrib += __shfl_down(contrib, off, 64);
  __shared__ float red[4];
  int lane = tid & 63, wid = tid >> 6;
  if (lane == 0) red[wid] = contrib;
  __syncthreads();
  if (tid == 0) atomicAdd(out, -2.f * (red[0] + red[1] + red[2] + red[3]));
}

extern "C" void kernel_launch(void* const* d_in, const int* in_sizes, int n_in,
                              void* d_out, int out_size, void* d_ws, size_t ws_size,
                              hipStream_t stream) {
  const float* x  = (const float*)d_in[0];
  const float* W1 = (const float*)d_in[1];
  const float* b1 = (const float*)d_in[2];
  const float* W2 = (const float*)d_in[3];
  const float* b2 = (const float*)d_in[4];
  const float* W3 = (const float*)d_in[5];
  // b3 (d_in[6]) vanishes under the Laplacian.
  float* out = (float*)d_out;
  float* ws = (float*)d_ws;

  if (ws_size >= WS_FAST_BYTES) {
    float* u0  = ws;                                         // byte 0
    float* q   = ws + 4096;                                  // byte 16384
    float* cv  = ws + 8192;                                  // byte 32768
    float* cdP = ws + 12288;                                 // byte 49152
    float* P   = ws + 12800;                                 // byte 51200
    unsigned int* cnts = (unsigned int*)((char*)d_ws + 53248);
    ushort_t* Ap = (ushort_t*)((char*)d_ws + 65536);
    ushort_t* Bp = (ushort_t*)((char*)d_ws + 33619968);
    hipLaunchKernelGGL(kA_l1t, dim3(512), dim3(256), 0, stream,
                       W1, x, b1, u0, q, Bp, cnts);
    hipLaunchKernelGGL(kBCD, dim3(512), dim3(256), 0, stream,
                       W2, b2, W3, u0, q, Ap, Bp, cv, cdP, P, cnts, out);
  } else {
    float* u0 = ws;
    float* q  = ws + 4096;
    float* s  = ws + 8192;
    float* cv = ws + 12288;
    hipLaunchKernelGGL(k1_slow, dim3(HH1), dim3(256), 0, stream,
                       W1, x, b1, u0, q, s, out);
    hipLaunchKernelGGL(k2_slow, dim3(HH2), dim3(256), 0, stream,
                       W2, b2, W3, u0, q, cv, out);
    hipLaunchKernelGGL(k4_slow, dim3(DD / 64, HH2 / 64), dim3(256), 0, stream,
                       W2, W1, s, cv, out);
  }
}